// Round 10
// baseline (237.208 us; speedup 1.0000x reference)
//
#include <hip/hip_runtime.h>
#include <hip/hip_cooperative_groups.h>
#include <cmath>

namespace cg = cooperative_groups;

#define EPS 1e-5f
#define SZ 2097152  // N*H*W*E = 4*64*64*128

typedef __attribute__((ext_vector_type(8))) short short8;   // 8 bf16 (4 VGPRs)
typedef __attribute__((ext_vector_type(4))) float floatx4;  // MFMA C/D frag

__device__ __forceinline__ float dot4(float4 a, float4 b) {
  return fmaf(a.x, b.x, fmaf(a.y, b.y, fmaf(a.z, b.z, a.w * b.w)));
}

__device__ __forceinline__ short f2bf(float f) {
  union { float f; unsigned u; } v; v.f = f;
  unsigned r = v.u + 0x7fff + ((v.u >> 16) & 1);  // RNE
  return (short)(r >> 16);
}

#define MFMA16(a, b, c) __builtin_amdgcn_mfma_f32_16x16x32_bf16(a, b, c, 0, 0, 0)

struct KParams {
  const float *x, *qcoeff, *wq, *bq, *wk, *bk, *wv, *bv, *rel_bias;
  const float *ln1_g, *ln1_b, *bil_w, *bil_b, *ln2_g, *ln2_b, *w1, *b1, *w2, *b2;
  float* out;
  float* x_nhwc;
  short *qbf, *kbf, *vtb;
  short *tb, *w1bf, *w2bf, *wqbf, *wkbf, *wvbf;
};

// One cooperative kernel: phase0 prep | grid.sync | phase1 LN1+QKV | grid.sync | phase2 attn+tail
// grid 256 = (n*64+y), block 1024 = 16 waves; 137 KB LDS -> exactly 1 block/CU, all co-resident
__global__ __launch_bounds__(1024) void k_all(KParams p) {
  __shared__ __align__(16) char smem[140544];
  cg::grid_group grid = cg::this_grid();
  int tid = threadIdx.x;
  int bid = blockIdx.x;
  int n = bid >> 6, y = bid & 63;

  // ================= phase 0: prep (weights fp32->bf16 padded 136; t = bil_w.qcoeff) =================
  {
    float* qs = (float*)smem;
    if (tid < 256) qs[tid] = p.qcoeff[tid];
    __syncthreads();
    int gtid = bid * 1024 + tid;      // 262144 threads
    if (gtid < 16384) {
      int flat = gtid * 4;
      {  // w1 [512f][128c] -> [512][136]
        int f = flat >> 7, c = flat & 127;
        float4 v = *(const float4*)&p.w1[flat];
        short t4[4] = {f2bf(v.x), f2bf(v.y), f2bf(v.z), f2bf(v.w)};
        *(uint2*)&p.w1bf[f * 136 + c] = *(uint2*)t4;
      }
      {  // w2 [128o][512j] -> 4 chunks [128o][136]
        int o = flat >> 9, j = flat & 511;
        int ck = j >> 7, jj = j & 127;
        float4 v = *(const float4*)&p.w2[flat];
        short t4[4] = {f2bf(v.x), f2bf(v.y), f2bf(v.z), f2bf(v.w)};
        *(uint2*)&p.w2bf[(ck * 128 + o) * 136 + jj] = *(uint2*)t4;
      }
      {  // t[n][o][i] = sum_q bil_w[o][i][q]*qcoeff[n][q]
        const float* wrow = p.bil_w + (size_t)gtid * 64;
        float acc[4] = {0.f, 0.f, 0.f, 0.f};
        for (int qq = 0; qq < 64; qq += 4) {
          float4 w4 = *(const float4*)&wrow[qq];
#pragma unroll
          for (int nn = 0; nn < 4; ++nn) {
            const float* qc = &qs[nn * 64 + qq];
            acc[nn] = fmaf(w4.x, qc[0], fmaf(w4.y, qc[1], fmaf(w4.z, qc[2], fmaf(w4.w, qc[3], acc[nn]))));
          }
        }
        int o = gtid >> 7, i = gtid & 127;
#pragma unroll
        for (int nn = 0; nn < 4; ++nn) p.tb[nn * 17408 + o * 136 + i] = f2bf(acc[nn]);
      }
    }
    if (gtid < 4096) {  // wq/wk/wv [128o][128c] -> [128][136]
      int flat = gtid * 4; int o = flat >> 7, c = flat & 127;
      float4 a = *(const float4*)&p.wq[flat];
      float4 b = *(const float4*)&p.wk[flat];
      float4 cc = *(const float4*)&p.wv[flat];
      short ta[4] = {f2bf(a.x), f2bf(a.y), f2bf(a.z), f2bf(a.w)};
      short tb4[4] = {f2bf(b.x), f2bf(b.y), f2bf(b.z), f2bf(b.w)};
      short tc[4] = {f2bf(cc.x), f2bf(cc.y), f2bf(cc.z), f2bf(cc.w)};
      *(uint2*)&p.wqbf[o * 136 + c] = *(uint2*)ta;
      *(uint2*)&p.wkbf[o * 136 + c] = *(uint2*)tb4;
      *(uint2*)&p.wvbf[o * 136 + c] = *(uint2*)tc;
    }
  }
  grid.sync();

  // ================= phase 1: LN1 + transpose + QKV -> qbf/kbf/vtb bf16 =================
  {
    float* tile = (float*)smem;                    // [128c][65] fp32, 33280 B
    float* mres = (float*)(smem + 33280);
    float* rres = (float*)(smem + 33536);
    short* xs = (short*)(smem + 34048);            // [64px][136] bf16
    short* ws = (short*)(smem + 51456);            // [128o][136] bf16
    const float* xb = p.x + (size_t)n * (128 * 4096) + y * 64;
    for (int it = 0; it < 8; ++it) {
      int flat = it * 1024 + tid;                  // c*64 + xp
      int c = flat >> 6, xp = flat & 63;
      tile[c * 65 + xp] = xb[(size_t)c * 4096 + xp];
    }
    __syncthreads();
    {
      int px = tid >> 4, cl = tid & 15;
      float s = 0.f, sq = 0.f;
#pragma unroll
      for (int j = 0; j < 8; ++j) {
        float v = tile[(cl * 8 + j) * 65 + px];
        s += v; sq += v * v;
      }
      s += __shfl_xor(s, 1);  sq += __shfl_xor(sq, 1);
      s += __shfl_xor(s, 2);  sq += __shfl_xor(sq, 2);
      s += __shfl_xor(s, 4);  sq += __shfl_xor(sq, 4);
      s += __shfl_xor(s, 8);  sq += __shfl_xor(sq, 8);
      if (cl == 0) {
        float m = s * (1.f / 128.f);
        float var = sq * (1.f / 128.f) - m * m;
        mres[px] = m;
        rres[px] = rsqrtf(var + EPS);
      }
    }
    __syncthreads();
    size_t rowbase = (size_t)bid * 8192;
    for (int it = 0; it < 8; ++it) {
      int flat = it * 1024 + tid;                  // px*128 + c
      int c = flat & 127, px = flat >> 7;
      float v = tile[c * 65 + px];
      p.x_nhwc[rowbase + flat] = v;
      xs[px * 136 + c] = f2bf((v - mres[px]) * rres[px] * p.ln1_g[c] + p.ln1_b[c]);
    }
    __syncthreads();
    int w = tid >> 6, lane = tid & 63;
    int quad = lane >> 4, r16 = lane & 15;
    int wm = w & 3, wn = w >> 2;
    int strip = wm * 16;
    short8 a[4];
#pragma unroll
    for (int kk = 0; kk < 4; ++kk)
      a[kk] = *(const short8*)&xs[(strip + r16) * 136 + kk * 32 + quad * 8];
    const short* wptr[3] = {p.wqbf, p.wkbf, p.wvbf};
    const float* bptr[3] = {p.bq, p.bk, p.bv};
    for (int m = 0; m < 3; ++m) {
      __syncthreads();
      const short* wp = wptr[m];
      for (int i = tid; i < 2176; i += 1024)
        *(short8*)&ws[i * 8] = *(const short8*)&wp[i * 8];
      __syncthreads();
      const float* bb = bptr[m];
#pragma unroll
      for (int nt = 0; nt < 2; ++nt) {
        int o0 = wn * 32 + nt * 16;
        floatx4 acc = {0.f, 0.f, 0.f, 0.f};
#pragma unroll
        for (int kk = 0; kk < 4; ++kk) {
          short8 bfr = *(const short8*)&ws[(o0 + r16) * 136 + kk * 32 + quad * 8];
          acc = MFMA16(a[kk], bfr, acc);
        }
        float bv2 = bb[o0 + r16];
        if (m < 2) {
          short* dst = (m == 0) ? p.qbf : p.kbf;
#pragma unroll
          for (int r = 0; r < 4; ++r) {
            int px = strip + quad * 4 + r;
            dst[rowbase + px * 128 + o0 + r16] = f2bf(acc[r] + bv2);
          }
        } else {
          short t4[4] = {f2bf(acc[0] + bv2), f2bf(acc[1] + bv2),
                         f2bf(acc[2] + bv2), f2bf(acc[3] + bv2)};
          *(uint2*)&p.vtb[(size_t)(n * 128 + o0 + r16) * 4096 + y * 64 + strip + quad * 4] =
              *(uint2*)t4;
        }
      }
    }
  }
  grid.sync();

  // ================= phase 2: attention + bilinear + LN2 + FFN + NCHW out =================
  short* z3s = (short*)(smem + 89344);
  float* z2s = (float*)(smem + 106752);
  int w16 = tid >> 6, lane = tid & 63;
  int quad = lane >> 4, r16 = lane & 15;
  // ---------- attention: wave = (h, sw) ----------
  {
    int h = w16 >> 2, sw = w16 & 3;
    int strip = sw * 16;
    float* ssfw = (float*)(smem + w16 * 3200);
    short* Abw = (short*)(smem + 51200 + w16 * 2176);
    float* biasw = (float*)(smem + 86016 + w16 * 208);
    {
      unsigned* ad = (unsigned*)Abw;
      for (int i = lane; i < 544; i += 64) ad[i] = 0u;
    }
    if (lane < 49) biasw[lane] = p.rel_bias[h * 49 + lane];
    const short* qrow = p.qbf + (size_t)n * 524288 + (size_t)y * 8192 + h * 32;
    short8 qf = *(const short8*)&qrow[(strip + r16) * 128 + quad * 8];
    const short* kbp = p.kbf + (size_t)n * 524288 + h * 32;
#pragma unroll
    for (int r = 0; r < 7; ++r) {
      int yy = y + r - 3;
      bool yok = (unsigned)yy < 64u;
      int yyc = min(max(yy, 0), 63);
#pragma unroll
      for (int t = 0; t < 2; ++t) {
        int xxc = (sw + t) * 16 + r16;
        int gx = xxc - 3;
        bool ok = yok && ((unsigned)gx < 64u);
        int gxc = min(max(gx, 0), 63);
        short8 bf = *(const short8*)&kbp[(size_t)(yyc * 64 + gxc) * 128 + quad * 8];
        floatx4 c = MFMA16(qf, bf, ((floatx4){0.f, 0.f, 0.f, 0.f}));
#pragma unroll
        for (int rr = 0; rr < 4; ++rr) {
          int lrow = quad * 4 + rr;
          int dx = xxc - (strip + lrow);
          if ((unsigned)dx < 7u) {
            float val = ok ? c[rr] : 0.f;           // reference zero-pads K
            ssfw[lrow * 50 + r * 7 + dx] = val + biasw[r * 7 + dx];
          }
        }
      }
    }
    {
      int lrow = lane >> 2, sub = lane & 3;
      int p0 = sub * 12, cnt = (sub == 3) ? 13 : 12;
      float sv[13];
      float mx = -1e30f;
      for (int pi = 0; pi < cnt; ++pi) { sv[pi] = ssfw[lrow * 50 + p0 + pi]; mx = fmaxf(mx, sv[pi]); }
      mx = fmaxf(mx, __shfl_xor(mx, 1));
      mx = fmaxf(mx, __shfl_xor(mx, 2));
      float sum = 0.f;
      for (int pi = 0; pi < cnt; ++pi) { float e = __expf(sv[pi] - mx); sv[pi] = e; sum += e; }
      sum += __shfl_xor(sum, 1);
      sum += __shfl_xor(sum, 2);
      float inv = 1.f / sum;
      for (int pi = 0; pi < cnt; ++pi) ssfw[lrow * 50 + p0 + pi] = sv[pi] * inv;
    }
    floatx4 oacc[2] = {(floatx4){0.f, 0.f, 0.f, 0.f}, (floatx4){0.f, 0.f, 0.f, 0.f}};
    int kk0 = (sw == 3) ? 1 : 0;
    int kk1 = (sw == 0) ? 0 : 1;
    int lrow = lane >> 2, sub = lane & 3;
    int pxg = strip + lrow;
    const short* vbp = p.vtb + (size_t)(n * 128 + h * 32) * 4096;
    for (int r = 0; r < 7; ++r) {
      int yy = y + r - 3;
      bool yok = (unsigned)yy < 64u;
      int yyc = min(max(yy, 0), 63);
      int c0 = pxg + sub - 3;
      if ((unsigned)c0 < 64u) Abw[lrow * 68 + c0] = f2bf(ssfw[lrow * 50 + r * 7 + sub]);
      int c1 = pxg + sub + 1;
      if (sub < 3 && (unsigned)c1 < 64u)
        Abw[lrow * 68 + c1] = f2bf(ssfw[lrow * 50 + r * 7 + sub + 4]);
      for (int kk = kk0; kk <= kk1; ++kk) {
        short8 af = *(const short8*)&Abw[r16 * 68 + kk * 32 + quad * 8];
#pragma unroll
        for (int nt = 0; nt < 2; ++nt) {
          short8 vf = *(const short8*)&vbp[(size_t)(nt * 16 + r16) * 4096 + yyc * 64 + kk * 32 + quad * 8];
          if (!yok) vf = (short8){0, 0, 0, 0, 0, 0, 0, 0};  // reference zero-pads V
          oacc[nt] = MFMA16(af, vf, oacc[nt]);
        }
      }
    }
#pragma unroll
    for (int nt = 0; nt < 2; ++nt)
#pragma unroll
      for (int rr = 0; rr < 4; ++rr) {
        int px = strip + quad * 4 + rr;
        z3s[px * 136 + h * 32 + nt * 16 + r16] = f2bf(oacc[nt][rr]);
      }
  }
  __syncthreads();
  // ---------- tail ----------
  short* R1s = (short*)smem;
  short* w2c = (short*)(smem + 34816);
  short* h1s = (short*)(smem + 69632);
  float* outt = (float*)smem;
  size_t rowbase = (size_t)bid * 8192;
  const short* tn = p.tb + (size_t)n * 17408;
  for (int i = tid; i < 2176; i += 1024)
    *(short8*)&R1s[i * 8] = *(const short8*)&tn[i * 8];
  __syncthreads();
  int wm = w16 & 3, wn = w16 >> 2;
  int strip = wm * 16;
  // bilinear
  {
    short8 a[4];
#pragma unroll
    for (int kk = 0; kk < 4; ++kk)
      a[kk] = *(const short8*)&z3s[(strip + r16) * 136 + kk * 32 + quad * 8];
#pragma unroll
    for (int nt = 0; nt < 2; ++nt) {
      int o0 = wn * 32 + nt * 16;
      floatx4 acc = {0.f, 0.f, 0.f, 0.f};
#pragma unroll
      for (int kk = 0; kk < 4; ++kk) {
        short8 bfr = *(const short8*)&R1s[(o0 + r16) * 136 + kk * 32 + quad * 8];
        acc = MFMA16(a[kk], bfr, acc);
      }
      float bb = p.bil_b[o0 + r16];
#pragma unroll
      for (int r = 0; r < 4; ++r) {
        int px = strip + quad * 4 + r;
        z2s[px * 132 + o0 + r16] = acc[r] + bb + p.x_nhwc[rowbase + px * 128 + o0 + r16];
      }
    }
  }
  __syncthreads();
  // LN2 -> z3s bf16
  {
    int px = tid >> 4, cl = tid & 15;
    float4 v0 = *(const float4*)&z2s[px * 132 + cl * 8];
    float4 v1 = *(const float4*)&z2s[px * 132 + cl * 8 + 4];
    float s = v0.x + v0.y + v0.z + v0.w + v1.x + v1.y + v1.z + v1.w;
    float sq = dot4(v0, v0) + dot4(v1, v1);
    s += __shfl_xor(s, 1);  sq += __shfl_xor(sq, 1);
    s += __shfl_xor(s, 2);  sq += __shfl_xor(sq, 2);
    s += __shfl_xor(s, 4);  sq += __shfl_xor(sq, 4);
    s += __shfl_xor(s, 8);  sq += __shfl_xor(sq, 8);
    float m = s * (1.f / 128.f);
    float var = sq * (1.f / 128.f) - m * m;
    float rr = rsqrtf(var + EPS);
    int c0 = cl * 8;
    short t8[8];
#pragma unroll
    for (int j = 0; j < 8; ++j) {
      float vv = (j < 4) ? (&v0.x)[j] : (&v1.x)[j - 4];
      t8[j] = f2bf((vv - m) * rr * p.ln2_g[c0 + j] + p.ln2_b[c0 + j]);
    }
    *(uint4*)&z3s[px * 136 + c0] = *(uint4*)t8;
  }
  __syncthreads();
  // FFN
  short8 a3[4];
#pragma unroll
  for (int kk = 0; kk < 4; ++kk)
    a3[kk] = *(const short8*)&z3s[(strip + r16) * 136 + kk * 32 + quad * 8];
  floatx4 zacc[2];
  zacc[0] = (floatx4){0.f, 0.f, 0.f, 0.f};
  zacc[1] = (floatx4){0.f, 0.f, 0.f, 0.f};
  for (int fc = 0; fc < 512; fc += 128) {
    __syncthreads();
    const short* w1src = p.w1bf + fc * 136;
    const short* w2src = p.w2bf + (fc >> 7) * 17408;
    for (int i = tid; i < 2176; i += 1024) {
      *(short8*)&R1s[i * 8] = *(const short8*)&w1src[i * 8];
      *(short8*)&w2c[i * 8] = *(const short8*)&w2src[i * 8];
    }
    __syncthreads();
#pragma unroll
    for (int nt = 0; nt < 2; ++nt) {
      int f0 = wn * 32 + nt * 16;
      floatx4 acc = {0.f, 0.f, 0.f, 0.f};
#pragma unroll
      for (int kk = 0; kk < 4; ++kk) {
        short8 bfr = *(const short8*)&R1s[(f0 + r16) * 136 + kk * 32 + quad * 8];
        acc = MFMA16(a3[kk], bfr, acc);
      }
      float bb1 = p.b1[fc + f0 + r16];
#pragma unroll
      for (int r = 0; r < 4; ++r) {
        float hv = acc[r] + bb1;
        float ge = 0.5f * hv * (1.f + erff(hv * 0.70710678118f));
        h1s[(strip + quad * 4 + r) * 136 + f0 + r16] = f2bf(ge);
      }
    }
    __syncthreads();
    short8 ah[4];
#pragma unroll
    for (int kk = 0; kk < 4; ++kk)
      ah[kk] = *(const short8*)&h1s[(strip + r16) * 136 + kk * 32 + quad * 8];
#pragma unroll
    for (int nt = 0; nt < 2; ++nt) {
      int o0 = wn * 32 + nt * 16;
#pragma unroll
      for (int kk = 0; kk < 4; ++kk) {
        short8 bfr = *(const short8*)&w2c[(o0 + r16) * 136 + kk * 32 + quad * 8];
        zacc[nt] = MFMA16(ah[kk], bfr, zacc[nt]);
      }
    }
  }
  __syncthreads();
#pragma unroll
  for (int nt = 0; nt < 2; ++nt) {
    int o0 = wn * 32 + nt * 16;
    float bb = p.b2[o0 + r16];
#pragma unroll
    for (int r = 0; r < 4; ++r) {
      int px = strip + quad * 4 + r;
      outt[(o0 + r16) * 65 + px] = zacc[nt][r] + bb + z2s[px * 132 + o0 + r16];
    }
  }
  __syncthreads();
  for (int it = 0; it < 8; ++it) {
    int flat = it * 1024 + tid;   // o*64 + px
    int o = flat >> 6, px = flat & 63;
    p.out[(((size_t)(n * 128 + o)) * 64 + y) * 64 + px] = outt[o * 65 + px];
  }
}

// ----------------------------------------------------------------
extern "C" void kernel_launch(void* const* d_in, const int* in_sizes, int n_in,
                              void* d_out, int out_size, void* d_ws, size_t ws_size,
                              hipStream_t stream) {
  float* ws = (float*)d_ws;
  short* bf = (short*)(ws + 4 * SZ);

  KParams p;
  p.x        = (const float*)d_in[0];
  p.qcoeff   = (const float*)d_in[1];
  p.wq       = (const float*)d_in[2];
  p.bq       = (const float*)d_in[3];
  p.wk       = (const float*)d_in[4];
  p.bk       = (const float*)d_in[5];
  p.wv       = (const float*)d_in[6];
  p.bv       = (const float*)d_in[7];
  p.rel_bias = (const float*)d_in[8];
  p.ln1_g    = (const float*)d_in[9];
  p.ln1_b    = (const float*)d_in[10];
  p.bil_w    = (const float*)d_in[11];
  p.bil_b    = (const float*)d_in[12];
  p.ln2_g    = (const float*)d_in[13];
  p.ln2_b    = (const float*)d_in[14];
  p.w1       = (const float*)d_in[15];
  p.b1       = (const float*)d_in[16];
  p.w2       = (const float*)d_in[17];
  p.b2       = (const float*)d_in[18];
  p.out      = (float*)d_out;
  p.x_nhwc   = ws;                       // [N,H,W,E] fp32 residual
  p.qbf      = (short*)(ws + 2 * SZ);    // bf16 NHWC
  p.kbf      = p.qbf + SZ;               // bf16 NHWC
  p.vtb      = p.kbf + SZ;               // bf16 transposed [n*128+o][4096]
  p.tb       = bf;                       // [4][128][136]
  p.w1bf     = bf + 4 * 17408;           // [512][136]
  p.w2bf     = p.w1bf + 512 * 136;       // [4][128][136]
  p.wqbf     = p.w2bf + 4 * 17408;       // [128][136]
  p.wkbf     = p.wqbf + 17408;
  p.wvbf     = p.wkbf + 17408;

  void* args[] = {&p};
  hipLaunchCooperativeKernel((const void*)k_all, dim3(256), dim3(1024), args, 0, stream);
}

// Round 11
// 149.405 us; speedup vs baseline: 1.5877x; 1.5877x over previous
//
#include <hip/hip_runtime.h>
#include <cmath>

#define EPS 1e-5f
#define SZ 2097152  // N*H*W*E = 4*64*64*128

typedef __attribute__((ext_vector_type(8))) short short8;   // 8 bf16 (4 VGPRs)
typedef __attribute__((ext_vector_type(4))) float floatx4;  // MFMA C/D frag

__device__ __forceinline__ float dot4(float4 a, float4 b) {
  return fmaf(a.x, b.x, fmaf(a.y, b.y, fmaf(a.z, b.z, a.w * b.w)));
}

__device__ __forceinline__ short f2bf(float f) {
  union { float f; unsigned u; } v; v.f = f;
  unsigned r = v.u + 0x7fff + ((v.u >> 16) & 1);  // RNE
  return (short)(r >> 16);
}

#define MFMA16(a, b, c) __builtin_amdgcn_mfma_f32_16x16x32_bf16(a, b, c, 0, 0, 0)

// ---------------------------------------------------------------- K0: prep (weights fp32->bf16 padded; t = bil_w.qcoeff)
// grid 64, block 256
__global__ __launch_bounds__(256) void k_prep(const float* __restrict__ w1,
    const float* __restrict__ w2, const float* __restrict__ wq,
    const float* __restrict__ wk, const float* __restrict__ wv,
    const float* __restrict__ bil_w, const float* __restrict__ qcoeff,
    short* __restrict__ w1bf, short* __restrict__ w2bf,
    short* __restrict__ wqbf, short* __restrict__ wkbf, short* __restrict__ wvbf,
    short* __restrict__ tb) {
  __shared__ float qs[256];
  int tid = threadIdx.x;
  qs[tid] = qcoeff[tid];
  __syncthreads();
  int tid0 = blockIdx.x * 256 + tid;
  int stride = gridDim.x * 256;
  for (int i = tid0; i < 16384; i += stride) {
    int flat = i * 4; int f = flat >> 7, c = flat & 127;
    float4 v = *(const float4*)&w1[flat];
    short t4[4] = {f2bf(v.x), f2bf(v.y), f2bf(v.z), f2bf(v.w)};
    *(uint2*)&w1bf[f * 136 + c] = *(uint2*)t4;
  }
  for (int i = tid0; i < 16384; i += stride) {
    int flat = i * 4; int o = flat >> 9, j = flat & 511;
    int ck = j >> 7, jj = j & 127;
    float4 v = *(const float4*)&w2[flat];
    short t4[4] = {f2bf(v.x), f2bf(v.y), f2bf(v.z), f2bf(v.w)};
    *(uint2*)&w2bf[(ck * 128 + o) * 136 + jj] = *(uint2*)t4;
  }
  for (int i = tid0; i < 4096; i += stride) {
    int flat = i * 4; int o = flat >> 7, c = flat & 127;
    float4 a = *(const float4*)&wq[flat];
    float4 b = *(const float4*)&wk[flat];
    float4 cc = *(const float4*)&wv[flat];
    short ta[4] = {f2bf(a.x), f2bf(a.y), f2bf(a.z), f2bf(a.w)};
    short tb4[4] = {f2bf(b.x), f2bf(b.y), f2bf(b.z), f2bf(b.w)};
    short tc[4] = {f2bf(cc.x), f2bf(cc.y), f2bf(cc.z), f2bf(cc.w)};
    *(uint2*)&wqbf[o * 136 + c] = *(uint2*)ta;
    *(uint2*)&wkbf[o * 136 + c] = *(uint2*)tb4;
    *(uint2*)&wvbf[o * 136 + c] = *(uint2*)tc;
  }
  {
    int flat = tid0;                          // o*128 + i
    const float* wrow = bil_w + (size_t)flat * 64;
    float acc[4] = {0.f, 0.f, 0.f, 0.f};
    for (int qq = 0; qq < 64; qq += 4) {
      float4 w4 = *(const float4*)&wrow[qq];
#pragma unroll
      for (int nn = 0; nn < 4; ++nn) {
        const float* qc = &qs[nn * 64 + qq];
        acc[nn] = fmaf(w4.x, qc[0], fmaf(w4.y, qc[1], fmaf(w4.z, qc[2], fmaf(w4.w, qc[3], acc[nn]))));
      }
    }
    int o = flat >> 7, i = flat & 127;
#pragma unroll
    for (int nn = 0; nn < 4; ++nn) tb[nn * 17408 + o * 136 + i] = f2bf(acc[nn]);
  }
}

// ---------------------------------------------------------------- K1: LN1 + transpose + QKV (LDS-staged weights)
// grid 512 = (n*64+y)*2+half, block 512 = 8 waves; 32 px/block; ~61 KB LDS -> 2 blocks/CU
__global__ __launch_bounds__(512) void k_qkvln(const float* __restrict__ x,
    const float* __restrict__ g, const float* __restrict__ b,
    const short* __restrict__ wqbf, const short* __restrict__ wkbf,
    const short* __restrict__ wvbf, const float* __restrict__ bq,
    const float* __restrict__ bk, const float* __restrict__ bv,
    float* __restrict__ xnhwc, short* __restrict__ qbf,
    short* __restrict__ kbf, short* __restrict__ vtb) {
  __shared__ float tile[128 * 33];               // x NCHW tile [c][xpl]
  __shared__ float mres[32], rres[32];
  __shared__ __align__(16) short xs[32 * 136];   // A: [pxl][c] bf16
  __shared__ __align__(16) short ws[128 * 136];  // B: [o][c] bf16 (staged per matrix)
  int tid = threadIdx.x;
  int bid = blockIdx.x;
  int half = bid & 1, ny = bid >> 1;
  int n = ny >> 6, y = ny & 63;
  const float* xb = x + (size_t)n * 524288 + y * 64 + half * 32;
  for (int it = 0; it < 8; ++it) {
    int flat = it * 512 + tid;                   // c*32 + xpl
    int c = flat >> 5, xpl = flat & 31;
    tile[c * 33 + xpl] = xb[(size_t)c * 4096 + xpl];
  }
  __syncthreads();
  {
    int pxl = tid >> 4, cl = tid & 15;
    float s = 0.f, sq = 0.f;
#pragma unroll
    for (int j = 0; j < 8; ++j) {
      float v = tile[(cl * 8 + j) * 33 + pxl];
      s += v; sq += v * v;
    }
    s += __shfl_xor(s, 1);  sq += __shfl_xor(sq, 1);
    s += __shfl_xor(s, 2);  sq += __shfl_xor(sq, 2);
    s += __shfl_xor(s, 4);  sq += __shfl_xor(sq, 4);
    s += __shfl_xor(s, 8);  sq += __shfl_xor(sq, 8);
    if (cl == 0) {
      float m = s * (1.f / 128.f);
      float var = sq * (1.f / 128.f) - m * m;
      mres[pxl] = m;
      rres[pxl] = rsqrtf(var + EPS);
    }
  }
  __syncthreads();
  size_t rowbase = (size_t)ny * 8192 + half * 4096;
  for (int it = 0; it < 8; ++it) {
    int flat = it * 512 + tid;                   // pxl*128 + c
    int c = flat & 127, pxl = flat >> 7;
    float v = tile[c * 33 + pxl];
    xnhwc[rowbase + flat] = v;
    xs[pxl * 136 + c] = f2bf((v - mres[pxl]) * rres[pxl] * g[c] + b[c]);
  }
  __syncthreads();
  int w = tid >> 6, lane = tid & 63;
  int quad = lane >> 4, r16 = lane & 15;
  int wm = w & 1, wn = w >> 1;                   // wn in [0,4)
  int stripl = wm * 16;
  short8 a[4];
#pragma unroll
  for (int kk = 0; kk < 4; ++kk)
    a[kk] = *(const short8*)&xs[(stripl + r16) * 136 + kk * 32 + quad * 8];
  const short* wptr[3] = {wqbf, wkbf, wvbf};
  const float* bptr[3] = {bq, bk, bv};
  for (int m = 0; m < 3; ++m) {
    __syncthreads();   // previous matrix's ws readers done
    const short* wp = wptr[m];
    for (int i = tid; i < 2176; i += 512)
      *(short8*)&ws[i * 8] = *(const short8*)&wp[i * 8];
    __syncthreads();
    const float* bb = bptr[m];
#pragma unroll
    for (int nt = 0; nt < 2; ++nt) {
      int o0 = wn * 32 + nt * 16;
      floatx4 acc = {0.f, 0.f, 0.f, 0.f};
#pragma unroll
      for (int kk = 0; kk < 4; ++kk) {
        short8 bfr = *(const short8*)&ws[(o0 + r16) * 136 + kk * 32 + quad * 8];
        acc = MFMA16(a[kk], bfr, acc);
      }
      float bv2 = bb[o0 + r16];
      if (m < 2) {
        short* dst = (m == 0) ? qbf : kbf;
#pragma unroll
        for (int r = 0; r < 4; ++r) {
          int pxl = stripl + quad * 4 + r;
          dst[rowbase + pxl * 128 + o0 + r16] = f2bf(acc[r] + bv2);
        }
      } else {
        short t4[4] = {f2bf(acc[0] + bv2), f2bf(acc[1] + bv2),
                       f2bf(acc[2] + bv2), f2bf(acc[3] + bv2)};
        *(uint2*)&vtb[(size_t)(n * 128 + o0 + r16) * 4096 + y * 64 + half * 32 +
                      stripl + quad * 4] = *(uint2*)t4;
      }
    }
  }
}

// ---------------------------------------------------------------- K2: attention + bilinear + LN2 + FFN + NCHW out (merged, R9)
// grid 256 = (n*64+y), block 1024 = 16 waves
__global__ __launch_bounds__(1024) void k_at(const short* __restrict__ qbf,
    const short* __restrict__ kbf, const short* __restrict__ vtb,
    const float* __restrict__ rel_bias, const short* __restrict__ tb,
    const float* __restrict__ bil_b, const float* __restrict__ xnhwc,
    const float* __restrict__ g2, const float* __restrict__ b2ln,
    const short* __restrict__ w1bf, const float* __restrict__ b1,
    const short* __restrict__ w2bf, const float* __restrict__ b2,
    float* __restrict__ out) {
  __shared__ __align__(16) char smem[140544];
  short* z3s = (short*)(smem + 89344);
  float* z2s = (float*)(smem + 106752);
  int tid = threadIdx.x;
  int bid = blockIdx.x;
  int n = bid >> 6, y = bid & 63;
  int w16 = tid >> 6, lane = tid & 63;
  int quad = lane >> 4, r16 = lane & 15;
  size_t rowbase = (size_t)bid * 8192;
  // prefetch bilinear residual (x_nhwc) into registers at kernel entry (hides VMEM latency)
  int wmE = w16 & 3, wnE = w16 >> 2;
  int stripE = wmE * 16;
  float xres[2][4];
#pragma unroll
  for (int nt = 0; nt < 2; ++nt)
#pragma unroll
    for (int r = 0; r < 4; ++r)
      xres[nt][r] = xnhwc[rowbase + (stripE + quad * 4 + r) * 128 + wnE * 32 + nt * 16 + r16];
  // ---------- attention phase: wave = (h, sw) ----------
  {
    int h = w16 >> 2, sw = w16 & 3;
    int strip = sw * 16;
    float* ssfw = (float*)(smem + w16 * 3200);
    short* Abw = (short*)(smem + 51200 + w16 * 2176);
    float* biasw = (float*)(smem + 86016 + w16 * 208);
    {
      unsigned* ad = (unsigned*)Abw;
      for (int i = lane; i < 544; i += 64) ad[i] = 0u;
    }
    if (lane < 49) biasw[lane] = rel_bias[h * 49 + lane];
    const short* qrow = qbf + (size_t)n * 524288 + (size_t)y * 8192 + h * 32;
    short8 qf = *(const short8*)&qrow[(strip + r16) * 128 + quad * 8];
    const short* kbp = kbf + (size_t)n * 524288 + h * 32;
#pragma unroll
    for (int r = 0; r < 7; ++r) {
      int yy = y + r - 3;
      bool yok = (unsigned)yy < 64u;
      int yyc = min(max(yy, 0), 63);
#pragma unroll
      for (int t = 0; t < 2; ++t) {
        int xxc = (sw + t) * 16 + r16;
        int gx = xxc - 3;
        bool ok = yok && ((unsigned)gx < 64u);
        int gxc = min(max(gx, 0), 63);
        short8 bf = *(const short8*)&kbp[(size_t)(yyc * 64 + gxc) * 128 + quad * 8];
        floatx4 c = MFMA16(qf, bf, ((floatx4){0.f, 0.f, 0.f, 0.f}));
#pragma unroll
        for (int rr = 0; rr < 4; ++rr) {
          int lrow = quad * 4 + rr;
          int dx = xxc - (strip + lrow);
          if ((unsigned)dx < 7u) {
            float val = ok ? c[rr] : 0.f;           // reference zero-pads K
            ssfw[lrow * 50 + r * 7 + dx] = val + biasw[r * 7 + dx];
          }
        }
      }
    }
    {
      int lrow = lane >> 2, sub = lane & 3;
      int p0 = sub * 12, cnt = (sub == 3) ? 13 : 12;
      float sv[13];
      float mx = -1e30f;
      for (int pi = 0; pi < cnt; ++pi) { sv[pi] = ssfw[lrow * 50 + p0 + pi]; mx = fmaxf(mx, sv[pi]); }
      mx = fmaxf(mx, __shfl_xor(mx, 1));
      mx = fmaxf(mx, __shfl_xor(mx, 2));
      float sum = 0.f;
      for (int pi = 0; pi < cnt; ++pi) { float e = __expf(sv[pi] - mx); sv[pi] = e; sum += e; }
      sum += __shfl_xor(sum, 1);
      sum += __shfl_xor(sum, 2);
      float inv = 1.f / sum;
      for (int pi = 0; pi < cnt; ++pi) ssfw[lrow * 50 + p0 + pi] = sv[pi] * inv;
    }
    floatx4 oacc[2] = {(floatx4){0.f, 0.f, 0.f, 0.f}, (floatx4){0.f, 0.f, 0.f, 0.f}};
    int kk0 = (sw == 3) ? 1 : 0;
    int kk1 = (sw == 0) ? 0 : 1;
    int lrow = lane >> 2, sub = lane & 3;
    int pxg = strip + lrow;
    const short* vbp = vtb + (size_t)(n * 128 + h * 32) * 4096;
    for (int r = 0; r < 7; ++r) {
      int yy = y + r - 3;
      bool yok = (unsigned)yy < 64u;
      int yyc = min(max(yy, 0), 63);
      int c0 = pxg + sub - 3;
      if ((unsigned)c0 < 64u) Abw[lrow * 68 + c0] = f2bf(ssfw[lrow * 50 + r * 7 + sub]);
      int c1 = pxg + sub + 1;
      if (sub < 3 && (unsigned)c1 < 64u)
        Abw[lrow * 68 + c1] = f2bf(ssfw[lrow * 50 + r * 7 + sub + 4]);
      for (int kk = kk0; kk <= kk1; ++kk) {
        short8 af = *(const short8*)&Abw[r16 * 68 + kk * 32 + quad * 8];
#pragma unroll
        for (int nt = 0; nt < 2; ++nt) {
          short8 vf = *(const short8*)&vbp[(size_t)(nt * 16 + r16) * 4096 + yyc * 64 + kk * 32 + quad * 8];
          if (!yok) vf = (short8){0, 0, 0, 0, 0, 0, 0, 0};  // reference zero-pads V
          oacc[nt] = MFMA16(af, vf, oacc[nt]);
        }
      }
    }
#pragma unroll
    for (int nt = 0; nt < 2; ++nt)
#pragma unroll
      for (int rr = 0; rr < 4; ++rr) {
        int px = strip + quad * 4 + rr;
        z3s[px * 136 + h * 32 + nt * 16 + r16] = f2bf(oacc[nt][rr]);
      }
  }
  __syncthreads();
  // ---------- tail phase ----------
  short* R1s = (short*)smem;
  short* w2c = (short*)(smem + 34816);
  short* h1s = (short*)(smem + 69632);
  float* outt = (float*)smem;
  const short* tn = tb + (size_t)n * 17408;
  for (int i = tid; i < 2176; i += 1024)
    *(short8*)&R1s[i * 8] = *(const short8*)&tn[i * 8];
  __syncthreads();
  int wm = w16 & 3, wn = w16 >> 2;
  int strip = wm * 16;
  // bilinear
  {
    short8 a[4];
#pragma unroll
    for (int kk = 0; kk < 4; ++kk)
      a[kk] = *(const short8*)&z3s[(strip + r16) * 136 + kk * 32 + quad * 8];
#pragma unroll
    for (int nt = 0; nt < 2; ++nt) {
      int o0 = wn * 32 + nt * 16;
      floatx4 acc = {0.f, 0.f, 0.f, 0.f};
#pragma unroll
      for (int kk = 0; kk < 4; ++kk) {
        short8 bfr = *(const short8*)&R1s[(o0 + r16) * 136 + kk * 32 + quad * 8];
        acc = MFMA16(a[kk], bfr, acc);
      }
      float bb = bil_b[o0 + r16];
#pragma unroll
      for (int r = 0; r < 4; ++r) {
        int px = strip + quad * 4 + r;
        z2s[px * 132 + o0 + r16] = acc[r] + bb + xres[nt][r];
      }
    }
  }
  __syncthreads();
  // LN2 -> z3s bf16
  {
    int px = tid >> 4, cl = tid & 15;
    float4 v0 = *(const float4*)&z2s[px * 132 + cl * 8];
    float4 v1 = *(const float4*)&z2s[px * 132 + cl * 8 + 4];
    float s = v0.x + v0.y + v0.z + v0.w + v1.x + v1.y + v1.z + v1.w;
    float sq = dot4(v0, v0) + dot4(v1, v1);
    s += __shfl_xor(s, 1);  sq += __shfl_xor(sq, 1);
    s += __shfl_xor(s, 2);  sq += __shfl_xor(sq, 2);
    s += __shfl_xor(s, 4);  sq += __shfl_xor(sq, 4);
    s += __shfl_xor(s, 8);  sq += __shfl_xor(sq, 8);
    float m = s * (1.f / 128.f);
    float var = sq * (1.f / 128.f) - m * m;
    float rr = rsqrtf(var + EPS);
    int c0 = cl * 8;
    short t8[8];
#pragma unroll
    for (int j = 0; j < 8; ++j) {
      float vv = (j < 4) ? (&v0.x)[j] : (&v1.x)[j - 4];
      t8[j] = f2bf((vv - m) * rr * g2[c0 + j] + b2ln[c0 + j]);
    }
    *(uint4*)&z3s[px * 136 + c0] = *(uint4*)t8;
  }
  __syncthreads();
  // FFN
  short8 a3[4];
#pragma unroll
  for (int kk = 0; kk < 4; ++kk)
    a3[kk] = *(const short8*)&z3s[(strip + r16) * 136 + kk * 32 + quad * 8];
  floatx4 zacc[2];
  zacc[0] = (floatx4){0.f, 0.f, 0.f, 0.f};
  zacc[1] = (floatx4){0.f, 0.f, 0.f, 0.f};
  for (int fc = 0; fc < 512; fc += 128) {
    __syncthreads();
    const short* w1src = w1bf + fc * 136;
    const short* w2src = w2bf + (fc >> 7) * 17408;
    for (int i = tid; i < 2176; i += 1024) {
      *(short8*)&R1s[i * 8] = *(const short8*)&w1src[i * 8];
      *(short8*)&w2c[i * 8] = *(const short8*)&w2src[i * 8];
    }
    __syncthreads();
#pragma unroll
    for (int nt = 0; nt < 2; ++nt) {
      int f0 = wn * 32 + nt * 16;
      floatx4 acc = {0.f, 0.f, 0.f, 0.f};
#pragma unroll
      for (int kk = 0; kk < 4; ++kk) {
        short8 bfr = *(const short8*)&R1s[(f0 + r16) * 136 + kk * 32 + quad * 8];
        acc = MFMA16(a3[kk], bfr, acc);
      }
      float bb1 = b1[fc + f0 + r16];
#pragma unroll
      for (int r = 0; r < 4; ++r) {
        float hv = acc[r] + bb1;
        float ge = 0.5f * hv * (1.f + erff(hv * 0.70710678118f));
        h1s[(strip + quad * 4 + r) * 136 + f0 + r16] = f2bf(ge);
      }
    }
    __syncthreads();
    short8 ah[4];
#pragma unroll
    for (int kk = 0; kk < 4; ++kk)
      ah[kk] = *(const short8*)&h1s[(strip + r16) * 136 + kk * 32 + quad * 8];
#pragma unroll
    for (int nt = 0; nt < 2; ++nt) {
      int o0 = wn * 32 + nt * 16;
#pragma unroll
      for (int kk = 0; kk < 4; ++kk) {
        short8 bfr = *(const short8*)&w2c[(o0 + r16) * 136 + kk * 32 + quad * 8];
        zacc[nt] = MFMA16(ah[kk], bfr, zacc[nt]);
      }
    }
  }
  __syncthreads();  // done with R1s/w2c/h1s -> outt alias safe
#pragma unroll
  for (int nt = 0; nt < 2; ++nt) {
    int o0 = wn * 32 + nt * 16;
    float bb = b2[o0 + r16];
#pragma unroll
    for (int r = 0; r < 4; ++r) {
      int px = strip + quad * 4 + r;
      outt[(o0 + r16) * 65 + px] = zacc[nt][r] + bb + z2s[px * 132 + o0 + r16];
    }
  }
  __syncthreads();
  for (int it = 0; it < 8; ++it) {
    int flat = it * 1024 + tid;   // o*64 + px
    int o = flat >> 6, px = flat & 63;
    out[(((size_t)(n * 128 + o)) * 64 + y) * 64 + px] = outt[o * 65 + px];
  }
}

// ----------------------------------------------------------------
extern "C" void kernel_launch(void* const* d_in, const int* in_sizes, int n_in,
                              void* d_out, int out_size, void* d_ws, size_t ws_size,
                              hipStream_t stream) {
  const float* x        = (const float*)d_in[0];
  const float* qcoeff   = (const float*)d_in[1];
  const float* wq       = (const float*)d_in[2];
  const float* bq       = (const float*)d_in[3];
  const float* wk       = (const float*)d_in[4];
  const float* bk       = (const float*)d_in[5];
  const float* wv       = (const float*)d_in[6];
  const float* bv       = (const float*)d_in[7];
  const float* rel_bias = (const float*)d_in[8];
  const float* ln1_g    = (const float*)d_in[9];
  const float* ln1_b    = (const float*)d_in[10];
  const float* bil_w    = (const float*)d_in[11];
  const float* bil_b    = (const float*)d_in[12];
  const float* ln2_g    = (const float*)d_in[13];
  const float* ln2_b    = (const float*)d_in[14];
  const float* w1       = (const float*)d_in[15];
  const float* b1       = (const float*)d_in[16];
  const float* w2       = (const float*)d_in[17];
  const float* b2       = (const float*)d_in[18];
  float* out = (float*)d_out;

  float* ws = (float*)d_ws;
  float* x_nhwc = ws;                    // [N,H,W,E] fp32 (residual source)
  short* qbf = (short*)(ws + 2 * SZ);    // bf16 NHWC
  short* kbf = qbf + SZ;                 // bf16 NHWC
  short* vtb = kbf + SZ;                 // bf16 transposed [n*128+o][4096]
  short* bf     = (short*)(ws + 4 * SZ); // bf16 weights
  short* tb     = bf;                    // [4][128][136]
  short* w1bf   = bf + 4 * 17408;        // [512][136]
  short* w2bf   = w1bf + 512 * 136;      // [4][128][136]
  short* wqbf   = w2bf + 4 * 17408;      // [128][136]
  short* wkbf   = wqbf + 17408;
  short* wvbf   = wkbf + 17408;

  k_prep<<<64, 256, 0, stream>>>(w1, w2, wq, wk, wv, bil_w, qcoeff,
                                 w1bf, w2bf, wqbf, wkbf, wvbf, tb);
  k_qkvln<<<512, 512, 0, stream>>>(x, ln1_g, ln1_b, wqbf, wkbf, wvbf,
                                   bq, bk, bv, x_nhwc, qbf, kbf, vtb);
  k_at<<<256, 1024, 0, stream>>>(qbf, kbf, vtb, rel_bias, tb, bil_b, x_nhwc,
                                 ln2_g, ln2_b, w1bf, b1, w2bf, b2, out);
}